// Round 1
// baseline (108.624 us; speedup 1.0000x reference)
//
#include <hip/hip_runtime.h>
#include <math.h>

// Problem constants
constexpr int B_ = 8;
constexpr int N_ = 400;
constexpr int D_ = 768;
constexpr int M_ = 160;                 // int(0.4 * 400)
constexpr int PAIRS_ = M_ * (M_ - 1);   // 25440
constexpr size_t BMD_ = (size_t)B_ * M_ * D_;  // 983,040 (rank-dense)
constexpr int NT_ = M_ / 16;            // 10 (16-row tiles per side)
constexpr int TRI_ = NT_ * (NT_ + 1) / 2;  // 55 upper-triangular tiles

typedef __attribute__((ext_vector_type(8))) short short8;   // 8 bf16 (4 VGPRs)
typedef __attribute__((ext_vector_type(4))) float floatx4;  // MFMA C/D

// Workspace layout (bytes), all rank-dense:
//   z     : double[B_*N_]     @ 0
//   aterm : float[B_*M_*3]    @ 30720   (includes b_pair)
//   bterm : float[B_*M_*3]    @ 46080
//   rr    : int[B_*M_*2]      @ 61440   (span_ranges gathered by rank)
//   Xbf   : short[BMD_]       @ 71680   (bf16 RNE of x, ranked rows)
//   Ybf   : short[3][BMD_]    @ 2037760 (bf16 RNE of x*w3_c, ranked rows)

// Packed f32->bf16 RNE (hardware): identical bits to the manual
// (u + 0x7fff + ((u>>16)&1)) >> 16 sequence for finite inputs.
__device__ __forceinline__ unsigned cvt_pk_bf16(float lo, float hi) {
  unsigned r;
  asm("v_cvt_pk_bf16_f32 %0, %1, %2" : "=v"(r) : "v"(lo), "v"(hi));
  return r;
}

// ---------------------------------------------------------------------------
// Kernel 1: z[row] = fp64 dot(x_row, w_span). One wave per row (all B*N).
// Sigmoid is monotonic -> rank on z.
__global__ __launch_bounds__(256) void k_span(const float* __restrict__ x,
                                              const float* __restrict__ w_span,
                                              double* __restrict__ z) {
  int row = blockIdx.x * 4 + (threadIdx.x >> 6);
  int lane = threadIdx.x & 63;
  const float* xr = x + (size_t)row * D_;
  double acc = 0.0;
#pragma unroll
  for (int it = 0; it < 3; ++it) {
    int d = it * 256 + lane * 4;
    float4 xv = *(const float4*)(xr + d);
    float4 wv = *(const float4*)(w_span + d);
    acc += (double)xv.x * wv.x + (double)xv.y * wv.y +
           (double)xv.z * wv.z + (double)xv.w * wv.w;
  }
#pragma unroll
  for (int off = 32; off > 0; off >>= 1)
    acc += __shfl_down(acc, off, 64);
  if (lane == 0) z[row] = acc;
}

// ---------------------------------------------------------------------------
// Kernel 2 (fused rank + prep): 40 blocks per batch; each block redundantly
// recomputes its batch's rank permutation in LDS (replaces the former 8-block
// k_rank launch), then each of its 4 waves preps one rank slot:
//   aterm[s,c] = dot(x, w1[:,c]) + b_pair[c];  bterm[s,c] = dot(x, w2[:,c])
//   Xbf[s]  = bf16(x);  Ybf[c][s] = bf16(x * w3[:,c]);  rr[s] = ranges[row]
__global__ __launch_bounds__(256) void k_prep_rank(const float* __restrict__ x,
                                                   const float* __restrict__ w_pair,
                                                   const float* __restrict__ b_pair,
                                                   const double* __restrict__ z,
                                                   const int* __restrict__ span_ranges,
                                                   float* __restrict__ aterm,
                                                   float* __restrict__ bterm,
                                                   int* __restrict__ rr,
                                                   short* __restrict__ Xbf,
                                                   short* __restrict__ Ybf) {
  __shared__ double zsh[N_];
  __shared__ int ranksh[M_];
  __shared__ int pos_sh[M_];
  int blk = blockIdx.x;
  int b = blk / 40;
  int t = threadIdx.x;

  for (int j = t; j < N_; j += 256) zsh[j] = z[b * N_ + j];
  __syncthreads();
  if (t < M_) {
    double zi = zsh[t];
    int cnt = 0;
    for (int j = 0; j < N_; ++j) {
      double zj = zsh[j];
      cnt += (zj > zi) || (zj == zi && j < t);
    }
    ranksh[t] = cnt;
  }
  __syncthreads();
  if (t < M_) {
    int r = ranksh[t];
    int slot = 0;
#pragma unroll 8
    for (int k = 0; k < M_; ++k) slot += (ranksh[k] < r);
    pos_sh[slot] = r;  // ranks distinct -> ascending sort
  }
  __syncthreads();

  int wid = t >> 6;
  int lane = t & 63;
  int i0 = (blk % 40) * 4 + wid;  // slot index within batch, [0,160)
  int s = b * M_ + i0;            // rank-dense slot
  int row = pos_sh[i0];           // source row (a rank value)
  const float* xr = x + ((size_t)(b * N_ + row)) * D_;
  const float* w3 = w_pair + 2 * D_ * 3;

  float a0 = 0, a1 = 0, a2 = 0, c0 = 0, c1 = 0, c2 = 0;
#pragma unroll
  for (int it = 0; it < 3; ++it) {
    int d = it * 256 + lane * 4;
    float4 xv = *(const float4*)(xr + d);
    float xf[4] = {xv.x, xv.y, xv.z, xv.w};

    float w1v[12], w2v[12], w3v[12];
#pragma unroll
    for (int q = 0; q < 3; ++q) {
      *(float4*)(w1v + 4 * q) = *(const float4*)(w_pair + (size_t)d * 3 + 4 * q);
      *(float4*)(w2v + 4 * q) = *(const float4*)(w_pair + (size_t)(D_ + d) * 3 + 4 * q);
      *(float4*)(w3v + 4 * q) = *(const float4*)(w3 + (size_t)d * 3 + 4 * q);
    }
#pragma unroll
    for (int e = 0; e < 4; ++e) {
      a0 += xf[e] * w1v[e * 3 + 0];
      a1 += xf[e] * w1v[e * 3 + 1];
      a2 += xf[e] * w1v[e * 3 + 2];
      c0 += xf[e] * w2v[e * 3 + 0];
      c1 += xf[e] * w2v[e * 3 + 1];
      c2 += xf[e] * w2v[e * 3 + 2];
    }

    size_t o = (size_t)s * D_ + d;
    uint2 xp;
    xp.x = cvt_pk_bf16(xf[0], xf[1]);
    xp.y = cvt_pk_bf16(xf[2], xf[3]);
    *(uint2*)(Xbf + o) = xp;
#pragma unroll
    for (int c = 0; c < 3; ++c) {
      uint2 yp;
      yp.x = cvt_pk_bf16(xf[0] * w3v[0 * 3 + c], xf[1] * w3v[1 * 3 + c]);
      yp.y = cvt_pk_bf16(xf[2] * w3v[2 * 3 + c], xf[3] * w3v[3 * 3 + c]);
      *(uint2*)(Ybf + (size_t)c * BMD_ + o) = yp;
    }
  }
#pragma unroll
  for (int off = 32; off > 0; off >>= 1) {
    a0 += __shfl_down(a0, off, 64);
    a1 += __shfl_down(a1, off, 64);
    a2 += __shfl_down(a2, off, 64);
    c0 += __shfl_down(c0, off, 64);
    c1 += __shfl_down(c1, off, 64);
    c2 += __shfl_down(c2, off, 64);
  }
  if (lane == 0) {
    aterm[s * 3 + 0] = a0 + b_pair[0];
    aterm[s * 3 + 1] = a1 + b_pair[1];
    aterm[s * 3 + 2] = a2 + b_pair[2];
    bterm[s * 3 + 0] = c0;
    bterm[s * 3 + 1] = c1;
    bterm[s * 3 + 2] = c2;
    *(int2*)(rr + s * 2) = *(const int2*)(span_ranges + row * 2);
  }
}

// ---------------------------------------------------------------------------
// Kernel 3 (MFMA pairs, symmetric): mult(i,j)@w3 is symmetric in (i,j), so
// only the 55 upper-triangular 16x16 tiles are computed (was 100). Diagonal
// tiles (ti==tj) contain both orientations natively; off-diagonal tiles emit
// both (i,j) and (j,i) from the same accumulator (only a/b terms swap roles).
__global__ __launch_bounds__(256) void k_pairs(const short* __restrict__ Xbf,
                                               const short* __restrict__ Ybf,
                                               const float* __restrict__ aterm,
                                               const float* __restrict__ bterm,
                                               const int* __restrict__ rr,
                                               float* __restrict__ out_probs,
                                               float4* __restrict__ out_ranges) {
  int lane = threadIdx.x & 63;
  int w = blockIdx.x * 4 + (threadIdx.x >> 6);  // 0..B*TRI-1 (440 waves)
  int b = w / TRI_;
  int t = w - b * TRI_;
  // triangular decode: ti <= tj (wave-uniform, <=10 iterations)
  int ti = 0, rem = t;
  while (rem >= NT_ - ti) { rem -= NT_ - ti; ++ti; }
  int tj = ti + rem;
  int quad = lane >> 4;
  int l16 = lane & 15;

  size_t oa = ((size_t)(b * M_ + ti * 16 + l16)) * D_ + quad * 8;
  size_t ob = ((size_t)(b * M_ + tj * 16 + l16)) * D_ + quad * 8;

  const short* ah0 = Ybf + 0 * BMD_ + oa;
  const short* ah1 = Ybf + 1 * BMD_ + oa;
  const short* ah2 = Ybf + 2 * BMD_ + oa;
  const short* bhp = Xbf + ob;

  floatx4 acc0 = {0.f, 0.f, 0.f, 0.f};
  floatx4 acc1 = {0.f, 0.f, 0.f, 0.f};
  floatx4 acc2 = {0.f, 0.f, 0.f, 0.f};

#pragma unroll 6
  for (int k = 0; k < D_; k += 32) {
    short8 bh = *(const short8*)(bhp + k);
    short8 h0 = *(const short8*)(ah0 + k);
    short8 h1 = *(const short8*)(ah1 + k);
    short8 h2 = *(const short8*)(ah2 + k);
    acc0 = __builtin_amdgcn_mfma_f32_16x16x32_bf16(h0, bh, acc0, 0, 0, 0);
    acc1 = __builtin_amdgcn_mfma_f32_16x16x32_bf16(h1, bh, acc1, 0, 0, 0);
    acc2 = __builtin_amdgcn_mfma_f32_16x16x32_bf16(h2, bh, acc2, 0, 0, 0);
  }

  // Epilogue. C/D layout: col = lane&15 (j side), row = quad*4 + reg (i side).
  const float* at = aterm + (size_t)(b * M_) * 3;
  const float* bt = bterm + (size_t)(b * M_) * 3;
  const int* rrb = rr + (size_t)(b * M_) * 2;
  bool offdiag = (ti != tj);
  int j = tj * 16 + l16;
  float bj0 = bt[j * 3 + 0], bj1 = bt[j * 3 + 1], bj2 = bt[j * 3 + 2];
  float aj0 = at[j * 3 + 0], aj1 = at[j * 3 + 1], aj2 = at[j * 3 + 2];
  int rj0 = rrb[j * 2 + 0], rj1 = rrb[j * 2 + 1];

#pragma unroll
  for (int r = 0; r < 4; ++r) {
    int i = ti * 16 + quad * 4 + r;
    float ai0 = at[i * 3 + 0], ai1 = at[i * 3 + 1], ai2 = at[i * 3 + 2];
    int ri0 = rrb[i * 2 + 0], ri1 = rrb[i * 2 + 1];

    // Orientation (i, j): logits = acc + a[i] + b[j]
    if (i != j) {
      float l0 = acc0[r] + ai0 + bj0;
      float l1 = acc1[r] + ai1 + bj1;
      float l2 = acc2[r] + ai2 + bj2;
      float s0 = 1.0f / (1.0f + expf(-l0));
      float s1 = 1.0f / (1.0f + expf(-l1));
      float s2 = 1.0f / (1.0f + expf(-l2));
      float e0 = expf(s0), e1 = expf(s1), e2 = expf(s2);
      float inv = 1.0f / (e0 + e1 + e2);
      int jj = j - (j > i ? 1 : 0);
      size_t p = (size_t)b * PAIRS_ + (size_t)i * (M_ - 1) + jj;
      out_probs[p * 3 + 0] = e0 * inv;
      out_probs[p * 3 + 1] = e1 * inv;
      out_probs[p * 3 + 2] = e2 * inv;
      float4 rg;
      rg.x = (float)ri0;
      rg.y = (float)ri1;
      rg.z = (float)rj0;
      rg.w = (float)rj1;
      out_ranges[p] = rg;
    }

    // Orientation (j, i): same acc (symmetric), logits = acc + a[j] + b[i]
    if (offdiag) {  // ti < tj -> i < j always, index adj for i is none
      float bi0 = bt[i * 3 + 0], bi1 = bt[i * 3 + 1], bi2 = bt[i * 3 + 2];
      float l0 = acc0[r] + aj0 + bi0;
      float l1 = acc1[r] + aj1 + bi1;
      float l2 = acc2[r] + aj2 + bi2;
      float s0 = 1.0f / (1.0f + expf(-l0));
      float s1 = 1.0f / (1.0f + expf(-l1));
      float s2 = 1.0f / (1.0f + expf(-l2));
      float e0 = expf(s0), e1 = expf(s1), e2 = expf(s2);
      float inv = 1.0f / (e0 + e1 + e2);
      size_t p = (size_t)b * PAIRS_ + (size_t)j * (M_ - 1) + i;
      out_probs[p * 3 + 0] = e0 * inv;
      out_probs[p * 3 + 1] = e1 * inv;
      out_probs[p * 3 + 2] = e2 * inv;
      float4 rg;
      rg.x = (float)rj0;
      rg.y = (float)rj1;
      rg.z = (float)ri0;
      rg.w = (float)ri1;
      out_ranges[p] = rg;
    }
  }
}

// ---------------------------------------------------------------------------
extern "C" void kernel_launch(void* const* d_in, const int* in_sizes, int n_in,
                              void* d_out, int out_size, void* d_ws, size_t ws_size,
                              hipStream_t stream) {
  const float* x = (const float*)d_in[0];
  const float* w_span = (const float*)d_in[1];
  // d_in[2] = b_span: constant shift, irrelevant to the ranking -> unused.
  const float* w_pair = (const float*)d_in[3];
  const float* b_pair = (const float*)d_in[4];
  const int* span_ranges = (const int*)d_in[5];

  char* ws = (char*)d_ws;
  double* z = (double*)ws;
  float* aterm = (float*)(ws + 30720);
  float* bterm = (float*)(ws + 46080);
  int* rr = (int*)(ws + 61440);
  short* Xbf = (short*)(ws + 71680);
  short* Ybf = (short*)(ws + 2037760);

  float* out = (float*)d_out;
  float* out_probs = out;                                         // B*P*3 floats
  float4* out_ranges = (float4*)(out + (size_t)B_ * PAIRS_ * 3);  // B*P*4 floats

  k_span<<<(B_ * N_) / 4, 256, 0, stream>>>(x, w_span, z);
  k_prep_rank<<<(B_ * M_) / 4, 256, 0, stream>>>(x, w_pair, b_pair, z,
                                                 span_ranges, aterm, bterm,
                                                 rr, Xbf, Ybf);
  k_pairs<<<(B_ * TRI_) / 4, 256, 0, stream>>>(Xbf, Ybf, aterm, bterm, rr,
                                               out_probs, out_ranges);
}

// Round 2
// 92.570 us; speedup vs baseline: 1.1734x; 1.1734x over previous
//
#include <hip/hip_runtime.h>
#include <math.h>

// Problem constants
constexpr int B_ = 8;
constexpr int N_ = 400;
constexpr int D_ = 768;
constexpr int M_ = 160;                 // int(0.4 * 400)
constexpr int PAIRS_ = M_ * (M_ - 1);   // 25440
constexpr size_t BMD_ = (size_t)B_ * M_ * D_;  // 983,040 (rank-dense)
constexpr int NT_ = M_ / 16;            // 10 (16-row tiles per side)
constexpr int TRI_ = NT_ * (NT_ + 1) / 2;  // 55 upper-triangular tiles

typedef __attribute__((ext_vector_type(8))) short short8;   // 8 bf16 (4 VGPRs)
typedef __attribute__((ext_vector_type(4))) float floatx4;  // MFMA C/D

// Workspace layout (bytes), all rank-dense:
//   z     : double[B_*N_]     @ 0
//   aterm : float[B_*M_*3]    @ 30720   (includes b_pair)
//   bterm : float[B_*M_*3]    @ 46080
//   rr    : int[B_*M_*2]      @ 61440   (span_ranges gathered by rank)
//   Xbf   : short[BMD_]       @ 71680   (bf16 RNE of x, ranked rows)
//   Ybf   : short[3][BMD_]    @ 2037760 (bf16 RNE of x*w3_c, ranked rows)

// Packed f32->bf16 RNE (hardware): identical bits to the manual
// (u + 0x7fff + ((u>>16)&1)) >> 16 sequence for finite inputs.
__device__ __forceinline__ unsigned cvt_pk_bf16(float lo, float hi) {
  unsigned r;
  asm("v_cvt_pk_bf16_f32 %0, %1, %2" : "=v"(r) : "v"(lo), "v"(hi));
  return r;
}

// ---------------------------------------------------------------------------
// Kernel 1: z[row] = fp64 dot(x_row, w_span). One wave per row (all B*N).
// Sigmoid is monotonic -> rank on z.
__global__ __launch_bounds__(256) void k_span(const float* __restrict__ x,
                                              const float* __restrict__ w_span,
                                              double* __restrict__ z) {
  int row = blockIdx.x * 4 + (threadIdx.x >> 6);
  int lane = threadIdx.x & 63;
  const float* xr = x + (size_t)row * D_;
  double acc = 0.0;
#pragma unroll
  for (int it = 0; it < 3; ++it) {
    int d = it * 256 + lane * 4;
    float4 xv = *(const float4*)(xr + d);
    float4 wv = *(const float4*)(w_span + d);
    acc += (double)xv.x * wv.x + (double)xv.y * wv.y +
           (double)xv.z * wv.z + (double)xv.w * wv.w;
  }
#pragma unroll
  for (int off = 32; off > 0; off >>= 1)
    acc += __shfl_down(acc, off, 64);
  if (lane == 0) z[row] = acc;
}

// ---------------------------------------------------------------------------
// Kernel 2 (fused rank + prep): 20 blocks x 512 threads per batch (160 blocks
// total = 1 per CU, no tail). Each block redundantly computes its batch's rank
// permutation in LDS with ALL 512 threads sharing the comparison work
// (each thread: <=3 owned rows x its wave's 50-j slice; zsh reads are
// wave-uniform -> LDS broadcast). Then each of its 8 waves preps one slot:
//   aterm[s,c] = dot(x, w1[:,c]) + b_pair[c];  bterm[s,c] = dot(x, w2[:,c])
//   Xbf[s]  = bf16(x);  Ybf[c][s] = bf16(x * w3[:,c]);  rr[s] = ranges[row]
__global__ __launch_bounds__(512) void k_prep_rank(const float* __restrict__ x,
                                                   const float* __restrict__ w_pair,
                                                   const float* __restrict__ b_pair,
                                                   const double* __restrict__ z,
                                                   const int* __restrict__ span_ranges,
                                                   float* __restrict__ aterm,
                                                   float* __restrict__ bterm,
                                                   int* __restrict__ rr,
                                                   short* __restrict__ Xbf,
                                                   short* __restrict__ Ybf) {
  __shared__ double zsh[N_];
  __shared__ int cnt8[8][M_];
  __shared__ int ranksh[M_];
  __shared__ int pos_sh[M_];
  int blk = blockIdx.x;
  int b = blk / 20;
  int t = threadIdx.x;
  int w = t >> 6;
  int lane = t & 63;

  if (t < N_) zsh[t] = z[b * N_ + t];
  __syncthreads();

  // Phase 2: partial descending-rank counts; wave w covers j in [50w, 50w+50).
  {
    double zi0 = zsh[lane];
    double zi1 = zsh[lane + 64];
    double zi2 = (lane < 32) ? zsh[lane + 128] : 0.0;
    int c0 = 0, c1 = 0, c2 = 0;
    int jb = w * 50;
    for (int q = 0; q < 50; ++q) {
      int jg = jb + q;
      double zj = zsh[jg];  // wave-uniform -> broadcast
      c0 += (zj > zi0) || (zj == zi0 && jg < lane);
      c1 += (zj > zi1) || (zj == zi1 && jg < lane + 64);
      c2 += (zj > zi2) || (zj == zi2 && jg < lane + 128);
    }
    cnt8[w][lane] = c0;
    cnt8[w][lane + 64] = c1;
    if (lane < 32) cnt8[w][lane + 128] = c2;
  }
  __syncthreads();
  if (t < M_) {
    int r = 0;
#pragma unroll
    for (int w2 = 0; w2 < 8; ++w2) r += cnt8[w2][t];
    ranksh[t] = r;
  }
  __syncthreads();
  // Phase 4: slot = #{k: rank_k < rank_i}; wave w covers k in [20w, 20w+20).
  {
    int ri0 = ranksh[lane];
    int ri1 = ranksh[lane + 64];
    int ri2 = (lane < 32) ? ranksh[lane + 128] : 0;
    int s0 = 0, s1 = 0, s2 = 0;
    int kb = w * 20;
    for (int q = 0; q < 20; ++q) {
      int rk = ranksh[kb + q];  // wave-uniform -> broadcast
      s0 += (rk < ri0);
      s1 += (rk < ri1);
      s2 += (rk < ri2);
    }
    cnt8[w][lane] = s0;  // reuse cnt8 for slot partials
    cnt8[w][lane + 64] = s1;
    if (lane < 32) cnt8[w][lane + 128] = s2;
  }
  __syncthreads();
  if (t < M_) {
    int s = 0;
#pragma unroll
    for (int w2 = 0; w2 < 8; ++w2) s += cnt8[w2][t];
    pos_sh[s] = ranksh[t];  // ranks distinct -> ascending sort
  }
  __syncthreads();

  // Prep: one wave per rank slot.
  int i0 = (blk % 20) * 8 + w;  // slot index within batch, [0,160)
  int s = b * M_ + i0;          // rank-dense slot
  int row = pos_sh[i0];         // source row (a rank value)
  const float* xr = x + ((size_t)(b * N_ + row)) * D_;
  const float* w3 = w_pair + 2 * D_ * 3;

  float a0 = 0, a1 = 0, a2 = 0, c0 = 0, c1 = 0, c2 = 0;
#pragma unroll
  for (int it = 0; it < 3; ++it) {
    int d = it * 256 + lane * 4;
    float4 xv = *(const float4*)(xr + d);
    float xf[4] = {xv.x, xv.y, xv.z, xv.w};

    float w1v[12], w2v[12], w3v[12];
#pragma unroll
    for (int q = 0; q < 3; ++q) {
      *(float4*)(w1v + 4 * q) = *(const float4*)(w_pair + (size_t)d * 3 + 4 * q);
      *(float4*)(w2v + 4 * q) = *(const float4*)(w_pair + (size_t)(D_ + d) * 3 + 4 * q);
      *(float4*)(w3v + 4 * q) = *(const float4*)(w3 + (size_t)d * 3 + 4 * q);
    }
#pragma unroll
    for (int e = 0; e < 4; ++e) {
      a0 += xf[e] * w1v[e * 3 + 0];
      a1 += xf[e] * w1v[e * 3 + 1];
      a2 += xf[e] * w1v[e * 3 + 2];
      c0 += xf[e] * w2v[e * 3 + 0];
      c1 += xf[e] * w2v[e * 3 + 1];
      c2 += xf[e] * w2v[e * 3 + 2];
    }

    size_t o = (size_t)s * D_ + d;
    uint2 xp;
    xp.x = cvt_pk_bf16(xf[0], xf[1]);
    xp.y = cvt_pk_bf16(xf[2], xf[3]);
    *(uint2*)(Xbf + o) = xp;
#pragma unroll
    for (int c = 0; c < 3; ++c) {
      uint2 yp;
      yp.x = cvt_pk_bf16(xf[0] * w3v[0 * 3 + c], xf[1] * w3v[1 * 3 + c]);
      yp.y = cvt_pk_bf16(xf[2] * w3v[2 * 3 + c], xf[3] * w3v[3 * 3 + c]);
      *(uint2*)(Ybf + (size_t)c * BMD_ + o) = yp;
    }
  }
#pragma unroll
  for (int off = 32; off > 0; off >>= 1) {
    a0 += __shfl_down(a0, off, 64);
    a1 += __shfl_down(a1, off, 64);
    a2 += __shfl_down(a2, off, 64);
    c0 += __shfl_down(c0, off, 64);
    c1 += __shfl_down(c1, off, 64);
    c2 += __shfl_down(c2, off, 64);
  }
  if (lane == 0) {
    aterm[s * 3 + 0] = a0 + b_pair[0];
    aterm[s * 3 + 1] = a1 + b_pair[1];
    aterm[s * 3 + 2] = a2 + b_pair[2];
    bterm[s * 3 + 0] = c0;
    bterm[s * 3 + 1] = c1;
    bterm[s * 3 + 2] = c2;
    *(int2*)(rr + s * 2) = *(const int2*)(span_ranges + row * 2);
  }
}

// ---------------------------------------------------------------------------
// Kernel 3 (MFMA pairs, symmetric + K-split-2): mult(i,j)@w3 is symmetric, so
// only 55 upper-triangular 16x16 tiles are computed. Each tile is owned by a
// PAIR of waves, each doing half of K (12 steps instead of 24 -> half the
// per-wave load-latency chain); partials combine through LDS. The two epilogue
// orientations (i,j) / (j,i) are split across the pair.
__global__ __launch_bounds__(256) void k_pairs(const short* __restrict__ Xbf,
                                               const short* __restrict__ Ybf,
                                               const float* __restrict__ aterm,
                                               const float* __restrict__ bterm,
                                               const int* __restrict__ rr,
                                               float* __restrict__ out_probs,
                                               float4* __restrict__ out_ranges) {
  __shared__ float accx[12][4][64];  // [acc reg][wave][lane]
  int lane = threadIdx.x & 63;
  int wl = threadIdx.x >> 6;  // 0..3
  int tl = wl >> 1;           // tile within block (0..1)
  int kh = wl & 1;            // K-half
  int tg = blockIdx.x * 2 + tl;  // global tile id, 0..B*TRI-1
  int b = tg / TRI_;
  int t = tg - b * TRI_;
  // triangular decode: ti <= tj (wave-uniform, <=10 iterations)
  int ti = 0, rem = t;
  while (rem >= NT_ - ti) { rem -= NT_ - ti; ++ti; }
  int tj = ti + rem;
  int quad = lane >> 4;
  int l16 = lane & 15;

  size_t oa = ((size_t)(b * M_ + ti * 16 + l16)) * D_ + quad * 8 + kh * 384;
  size_t ob = ((size_t)(b * M_ + tj * 16 + l16)) * D_ + quad * 8 + kh * 384;

  const short* ah0 = Ybf + 0 * BMD_ + oa;
  const short* ah1 = Ybf + 1 * BMD_ + oa;
  const short* ah2 = Ybf + 2 * BMD_ + oa;
  const short* bhp = Xbf + ob;

  floatx4 acc0 = {0.f, 0.f, 0.f, 0.f};
  floatx4 acc1 = {0.f, 0.f, 0.f, 0.f};
  floatx4 acc2 = {0.f, 0.f, 0.f, 0.f};

#pragma unroll
  for (int k = 0; k < 384; k += 32) {
    short8 bh = *(const short8*)(bhp + k);
    short8 h0 = *(const short8*)(ah0 + k);
    short8 h1 = *(const short8*)(ah1 + k);
    short8 h2 = *(const short8*)(ah2 + k);
    acc0 = __builtin_amdgcn_mfma_f32_16x16x32_bf16(h0, bh, acc0, 0, 0, 0);
    acc1 = __builtin_amdgcn_mfma_f32_16x16x32_bf16(h1, bh, acc1, 0, 0, 0);
    acc2 = __builtin_amdgcn_mfma_f32_16x16x32_bf16(h2, bh, acc2, 0, 0, 0);
  }

  // Combine K-halves across the wave pair (partner = wl^1).
#pragma unroll
  for (int r = 0; r < 4; ++r) {
    accx[r][wl][lane] = acc0[r];
    accx[4 + r][wl][lane] = acc1[r];
    accx[8 + r][wl][lane] = acc2[r];
  }
  __syncthreads();
  int pw = wl ^ 1;
#pragma unroll
  for (int r = 0; r < 4; ++r) {
    acc0[r] += accx[r][pw][lane];
    acc1[r] += accx[4 + r][pw][lane];
    acc2[r] += accx[8 + r][pw][lane];
  }

  bool diag = (ti == tj);
  if (diag && kh == 1) return;  // diag tile has only one orientation pass

  // Epilogue. C/D layout: col = lane&15 (j side), row = quad*4 + reg (i side).
  const float* at = aterm + (size_t)(b * M_) * 3;
  const float* bt = bterm + (size_t)(b * M_) * 3;
  const int* rrb = rr + (size_t)(b * M_) * 2;
  int j = tj * 16 + l16;
  int rj0 = rrb[j * 2 + 0], rj1 = rrb[j * 2 + 1];

  if (kh == 0) {
    // Orientation (i, j): logits = acc + a[i] + b[j]
    float bj0 = bt[j * 3 + 0], bj1 = bt[j * 3 + 1], bj2 = bt[j * 3 + 2];
#pragma unroll
    for (int r = 0; r < 4; ++r) {
      int i = ti * 16 + quad * 4 + r;
      if (i == j) continue;
      float l0 = acc0[r] + at[i * 3 + 0] + bj0;
      float l1 = acc1[r] + at[i * 3 + 1] + bj1;
      float l2 = acc2[r] + at[i * 3 + 2] + bj2;
      float s0 = 1.0f / (1.0f + expf(-l0));
      float s1 = 1.0f / (1.0f + expf(-l1));
      float s2 = 1.0f / (1.0f + expf(-l2));
      float e0 = expf(s0), e1 = expf(s1), e2 = expf(s2);
      float inv = 1.0f / (e0 + e1 + e2);
      int jj = j - (j > i ? 1 : 0);
      size_t p = (size_t)b * PAIRS_ + (size_t)i * (M_ - 1) + jj;
      out_probs[p * 3 + 0] = e0 * inv;
      out_probs[p * 3 + 1] = e1 * inv;
      out_probs[p * 3 + 2] = e2 * inv;
      float4 rg;
      rg.x = (float)rrb[i * 2 + 0];
      rg.y = (float)rrb[i * 2 + 1];
      rg.z = (float)rj0;
      rg.w = (float)rj1;
      out_ranges[p] = rg;
    }
  } else {
    // Orientation (j, i): same acc (symmetric); ti<tj -> i<j always.
    float aj0 = at[j * 3 + 0], aj1 = at[j * 3 + 1], aj2 = at[j * 3 + 2];
#pragma unroll
    for (int r = 0; r < 4; ++r) {
      int i = ti * 16 + quad * 4 + r;
      float l0 = acc0[r] + aj0 + bt[i * 3 + 0];
      float l1 = acc1[r] + aj1 + bt[i * 3 + 1];
      float l2 = acc2[r] + aj2 + bt[i * 3 + 2];
      float s0 = 1.0f / (1.0f + expf(-l0));
      float s1 = 1.0f / (1.0f + expf(-l1));
      float s2 = 1.0f / (1.0f + expf(-l2));
      float e0 = expf(s0), e1 = expf(s1), e2 = expf(s2);
      float inv = 1.0f / (e0 + e1 + e2);
      size_t p = (size_t)b * PAIRS_ + (size_t)j * (M_ - 1) + i;
      out_probs[p * 3 + 0] = e0 * inv;
      out_probs[p * 3 + 1] = e1 * inv;
      out_probs[p * 3 + 2] = e2 * inv;
      float4 rg;
      rg.x = (float)rj0;
      rg.y = (float)rj1;
      rg.z = (float)rrb[i * 2 + 0];
      rg.w = (float)rrb[i * 2 + 1];
      out_ranges[p] = rg;
    }
  }
}

// ---------------------------------------------------------------------------
extern "C" void kernel_launch(void* const* d_in, const int* in_sizes, int n_in,
                              void* d_out, int out_size, void* d_ws, size_t ws_size,
                              hipStream_t stream) {
  const float* x = (const float*)d_in[0];
  const float* w_span = (const float*)d_in[1];
  // d_in[2] = b_span: constant shift, irrelevant to the ranking -> unused.
  const float* w_pair = (const float*)d_in[3];
  const float* b_pair = (const float*)d_in[4];
  const int* span_ranges = (const int*)d_in[5];

  char* ws = (char*)d_ws;
  double* z = (double*)ws;
  float* aterm = (float*)(ws + 30720);
  float* bterm = (float*)(ws + 46080);
  int* rr = (int*)(ws + 61440);
  short* Xbf = (short*)(ws + 71680);
  short* Ybf = (short*)(ws + 2037760);

  float* out = (float*)d_out;
  float* out_probs = out;                                         // B*P*3 floats
  float4* out_ranges = (float4*)(out + (size_t)B_ * PAIRS_ * 3);  // B*P*4 floats

  k_span<<<(B_ * N_) / 4, 256, 0, stream>>>(x, w_span, z);
  k_prep_rank<<<B_ * 20, 512, 0, stream>>>(x, w_pair, b_pair, z,
                                           span_ranges, aterm, bterm,
                                           rr, Xbf, Ybf);
  k_pairs<<<(B_ * TRI_) / 2, 256, 0, stream>>>(Xbf, Ybf, aterm, bterm, rr,
                                               out_probs, out_ranges);
}